// Round 4
// baseline (280.913 us; speedup 1.0000x reference)
//
#include <hip/hip_runtime.h>
#include <hip/hip_cooperative_groups.h>

namespace cg = cooperative_groups;

// Problem constants
#define B_ 4096
#define S_ 32
#define K_ 1024
#define D_ 128
constexpr float DECAY = 0.99f;
constexpr float OMD   = 0.01f;     // 1 - decay
constexpr float EPS   = 1e-5f;

typedef float f4 __attribute__((ext_vector_type(4)));

#define NBLK 1024
#define ROWS_PER_BLK (B_ * S_ / NBLK)   // 128 rows per block

// ws layout: [0, S_*K_) int counts ; then S_ floats n[s]
//
// Single cooperative kernel, 3 phases:
//  A: zero counts (atomicExch -> coherence point), n[s] = DECAY*rowsum(ecs)+OMD*B
//     (sum_k counts == B exactly), and the big z_q gather-copy (hides the init).
//  B: histogram atomics, one row per thread.
//  C: fused EMA + Laplace: ne = d*ecs+omd*c ; cs = (ne+e)/(n+Ke)*n ;
//     nw = d*w + omd*c*emb (dw == counts*emb) ; nb = nw/cs.
// Working set (135 MB) < 256 MB L3 -> stay cacheable (NO nontemporal hints).
__global__ void __launch_bounds__(256, 4)
fused_kernel(const int* __restrict__ idx,
             const float* __restrict__ emb,
             const float* __restrict__ ecs_in,
             const float* __restrict__ ema_w,
             float* __restrict__ z_q,
             float* __restrict__ new_emb,
             float* __restrict__ new_ecs,
             float* __restrict__ new_ema_w,
             int* __restrict__ counts,
             float* __restrict__ n_arr) {
    cg::grid_group grid = cg::this_grid();
    const int b    = blockIdx.x;
    const int t    = threadIdx.x;
    const int g    = t >> 5;
    const int lane = t & 31;

    // ---- Phase A ----
    // Zero this block's 32-int slice of counts via atomics (device coherence point).
    if (t < 32) atomicExch(&counts[b * 32 + t], 0);

    // Blocks 0..31: n[s] rowsum of ecs_in (1024 floats = 256 x f4).
    __shared__ float red[4];
    if (b < S_) {
        const f4 v = reinterpret_cast<const f4*>(ecs_in + b * K_)[t];
        float local = v.x + v.y + v.z + v.w;
#pragma unroll
        for (int off = 1; off < 64; off <<= 1) local += __shfl_xor(local, off);
        if ((t & 63) == 0) red[t >> 6] = local;
        __syncthreads();
        if (t == 0)
            n_arr[b] = DECAY * (red[0] + red[1] + red[2] + red[3])
                     + OMD * (float)B_;
    }

    // z_q gather-copy: 128 rows/block, 8 groups x 16 iterations, f4 per lane.
    const int rowbase = b * ROWS_PER_BLK;
#pragma unroll 4
    for (int i = 0; i < ROWS_PER_BLK / 8; ++i) {
        const int row = rowbase + i * 8 + g;
        const int k   = idx[row];            // broadcast within 32-lane group
        const int s   = row & (S_ - 1);      // S_ = 32
        const f4 val  = reinterpret_cast<const f4*>(emb)[(size_t)(s * K_ + k) * 32 + lane];
        reinterpret_cast<f4*>(z_q)[(size_t)row * 32 + lane] = val;
    }

    grid.sync();

    // ---- Phase B: histogram (one row per thread, idx re-read is L1/L2-hot) ----
    if (t < ROWS_PER_BLK) {
        const int row = rowbase + t;
        const int k   = idx[row];
        atomicAdd(&counts[(row & (S_ - 1)) * K_ + k], 1);
    }

    grid.sync();

    // ---- Phase C: fused EMA elementwise, 1024 f4 per block ----
#pragma unroll
    for (int i = 0; i < 4; ++i) {
        const size_t e = (size_t)b * 1024 + i * 256 + t;  // f4 index
        const int sk = (int)(e >> 5);                     // 32 f4 per (s,k)
        const int s  = sk >> 10;                          // K_ = 1024
        const float c  = (float)counts[sk];
        const float ne = DECAY * ecs_in[sk] + OMD * c;
        const float n  = n_arr[s];
        const float cs = (ne + EPS) / (n + (float)K_ * EPS) * n;
        if ((e & 31) == 0) new_ecs[sk] = ne;

        const f4 w  = reinterpret_cast<const f4*>(ema_w)[e];
        const f4 em = reinterpret_cast<const f4*>(emb)[e];
        f4 nw;
        nw.x = DECAY * w.x + OMD * c * em.x;
        nw.y = DECAY * w.y + OMD * c * em.y;
        nw.z = DECAY * w.z + OMD * c * em.z;
        nw.w = DECAY * w.w + OMD * c * em.w;
        reinterpret_cast<f4*>(new_ema_w)[e] = nw;
        const float inv = 1.0f / cs;
        f4 nb;
        nb.x = nw.x * inv;
        nb.y = nw.y * inv;
        nb.z = nw.z * inv;
        nb.w = nw.w * inv;
        reinterpret_cast<f4*>(new_emb)[e] = nb;
    }
}

extern "C" void kernel_launch(void* const* d_in, const int* in_sizes, int n_in,
                              void* d_out, int out_size, void* d_ws, size_t ws_size,
                              hipStream_t stream) {
    const int*   idx   = (const int*)d_in[0];
    const float* emb   = (const float*)d_in[1];
    const float* ecs   = (const float*)d_in[2];
    const float* ema_w = (const float*)d_in[3];

    float* out       = (float*)d_out;
    float* z_q       = out;                                  // [B,S,D]
    float* new_emb   = z_q + (size_t)B_ * S_ * D_;           // [S,K,D]
    float* new_ecs   = new_emb + (size_t)S_ * K_ * D_;       // [S,K]
    float* new_ema_w = new_ecs + (size_t)S_ * K_;            // [S,K,D]

    int*   counts = (int*)d_ws;                              // S*K ints
    float* n_arr  = (float*)d_ws + (size_t)S_ * K_;          // S floats

    void* args[] = {(void*)&idx, (void*)&emb, (void*)&ecs, (void*)&ema_w,
                    (void*)&z_q, (void*)&new_emb, (void*)&new_ecs,
                    (void*)&new_ema_w, (void*)&counts, (void*)&n_arr};
    hipLaunchCooperativeKernel((const void*)fused_kernel,
                               dim3(NBLK), dim3(256), args, 0, stream);
}

// Round 6
// 35.751 us; speedup vs baseline: 7.8574x; 7.8574x over previous
//
#include <hip/hip_runtime.h>

// Problem constants
#define B_ 4096
#define S_ 32
#define K_ 1024
#define D_ 128
constexpr float DECAY = 0.99f;
constexpr float OMD   = 0.01f;     // 1 - decay
constexpr float EPS   = 1e-5f;

typedef float f4 __attribute__((ext_vector_type(4)));
typedef int   i4 __attribute__((ext_vector_type(4)));

// ws layout: [0, S_*K_) int counts ; then S_ floats n[s]

// Kernel 0: zero histogram + n[s] in closed form.
// n[s] = DECAY * rowsum(ecs_in[s,:]) + OMD * B   (sum_k counts[s,k] == B exactly)
__global__ void __launch_bounds__(256)
init_kernel(const float* __restrict__ ecs_in,
            int* __restrict__ counts,
            float* __restrict__ n_out) {
    const int s = blockIdx.x;
    const int t = threadIdx.x;
    reinterpret_cast<i4*>(counts + s * K_)[t] = i4{0, 0, 0, 0};
    const f4 v = reinterpret_cast<const f4*>(ecs_in + s * K_)[t];
    float local = v.x + v.y + v.z + v.w;
#pragma unroll
    for (int off = 1; off < 64; off <<= 1) local += __shfl_xor(local, off);
    __shared__ float red[4];
    if ((t & 63) == 0) red[t >> 6] = local;
    __syncthreads();
    if (t == 0)
        n_out[s] = DECAY * (red[0] + red[1] + red[2] + red[3]) + OMD * (float)B_;
}

// Kernel 1: fused z_q gather + histogram, s-major block mapping.
// s = blockIdx & 31  =>  all 512 blocks of a given s dispatch to XCD s%8
// (round-robin blockIdx%8), pinning that s's 512KB emb slice in ONE L2
// (4 slices = 2MB per XCD). Histogram atomics for s also stay on-XCD.
// 8 rows/block (same s, consecutive b), 32 lanes x f4 per row.
__global__ void __launch_bounds__(256)
gather_hist_kernel(const int* __restrict__ idx,
                   const float* __restrict__ emb,
                   float* __restrict__ z_q,
                   int* __restrict__ counts) {
    const int s     = blockIdx.x & (S_ - 1);
    const int chunk = blockIdx.x >> 5;          // [0, 512)
    const int g     = threadIdx.x >> 5;         // row group 0..7
    const int lane  = threadIdx.x & 31;
    const int b     = chunk * 8 + g;
    const int row   = b * S_ + s;
    const int k     = idx[row];                 // broadcast within 32-lane group
    if (lane == 0) atomicAdd(&counts[s * K_ + k], 1);
    const f4 val =
        reinterpret_cast<const f4*>(emb)[((size_t)s * K_ + k) * 32 + lane];
    __builtin_nontemporal_store(
        val, reinterpret_cast<f4*>(z_q) + (size_t)row * 32 + lane);
}

// Kernel 2: fused EMA + Laplace, XCD-aligned s mapping so emb re-reads hit
// the L2 the gather warmed: block i covers s = i&31 (so XCD i%8 == s%8),
// chunk c = i>>5 of 32 (s,k) bins; 4 f4 per thread => 1024 blocks total.
__global__ void __launch_bounds__(256)
ema_kernel(const float* __restrict__ ema_w,
           const float* __restrict__ emb,
           const float* __restrict__ ecs_in,
           const int* __restrict__ counts,
           const float* __restrict__ n_arr,
           float* __restrict__ new_ecs_out,
           float* __restrict__ new_ema_w_out,
           float* __restrict__ new_emb_out) {
    const int i = blockIdx.x;                         // [0, 1024)
    const int s = i & (S_ - 1);                       // [0, 32); s%8 == i%8
    const int c = i >> 5;                             // [0, 32) chunk within s
    const size_t base = ((size_t)s * K_ + c * 32) * 32;   // f4 base
    const float n = n_arr[s];
    const float denom_inv = 1.0f / (n + (float)K_ * EPS);
#pragma unroll
    for (int it = 0; it < 4; ++it) {
        const size_t e = base + it * 256 + threadIdx.x;   // f4 index
        const int sk = (int)(e >> 5);                     // 32 f4 per (s,k)
        const float ccount = (float)counts[sk];
        const float ne = DECAY * ecs_in[sk] + OMD * ccount;
        const float cs = (ne + EPS) * denom_inv * n;
        if ((e & 31) == 0) new_ecs_out[sk] = ne;

        const f4 w  = reinterpret_cast<const f4*>(ema_w)[e];  // plain load: L3-resident across replays
        const f4 em = reinterpret_cast<const f4*>(emb)[e];
        f4 nw;
        nw.x = DECAY * w.x + OMD * ccount * em.x;
        nw.y = DECAY * w.y + OMD * ccount * em.y;
        nw.z = DECAY * w.z + OMD * ccount * em.z;
        nw.w = DECAY * w.w + OMD * ccount * em.w;
        __builtin_nontemporal_store(
            nw, reinterpret_cast<f4*>(new_ema_w_out) + e);
        const float inv = 1.0f / cs;
        f4 nb;
        nb.x = nw.x * inv;
        nb.y = nw.y * inv;
        nb.z = nw.z * inv;
        nb.w = nw.w * inv;
        __builtin_nontemporal_store(
            nb, reinterpret_cast<f4*>(new_emb_out) + e);
    }
}

extern "C" void kernel_launch(void* const* d_in, const int* in_sizes, int n_in,
                              void* d_out, int out_size, void* d_ws, size_t ws_size,
                              hipStream_t stream) {
    const int*   idx   = (const int*)d_in[0];
    const float* emb   = (const float*)d_in[1];
    const float* ecs   = (const float*)d_in[2];
    const float* ema_w = (const float*)d_in[3];

    float* out       = (float*)d_out;
    float* z_q       = out;                                  // [B,S,D]
    float* new_emb   = z_q + (size_t)B_ * S_ * D_;           // [S,K,D]
    float* new_ecs   = new_emb + (size_t)S_ * K_ * D_;       // [S,K]
    float* new_ema_w = new_ecs + (size_t)S_ * K_;            // [S,K,D]

    int*   counts = (int*)d_ws;                              // S*K ints
    float* n_arr  = (float*)d_ws + (size_t)S_ * K_;          // S floats

    init_kernel<<<S_, 256, 0, stream>>>(ecs, counts, n_arr);
    gather_hist_kernel<<<(B_ * S_) / 8, 256, 0, stream>>>(idx, emb, z_q, counts);
    // 1024 blocks: each covers 1024 f4 (4 iters x 256 threads).
    ema_kernel<<<1024, 256, 0, stream>>>(
        ema_w, emb, ecs, counts, n_arr, new_ecs, new_ema_w, new_emb);
}

// Round 7
// 31.517 us; speedup vs baseline: 8.9131x; 1.1344x over previous
//
#include <hip/hip_runtime.h>

// Problem constants
#define B_ 4096
#define S_ 32
#define K_ 1024
#define D_ 128
constexpr float DECAY = 0.99f;
constexpr float OMD   = 0.01f;     // 1 - decay
constexpr float EPS   = 1e-5f;

typedef float          f4  __attribute__((ext_vector_type(4)));
typedef int            i4  __attribute__((ext_vector_type(4)));
typedef unsigned short u16;
typedef u16            us8 __attribute__((ext_vector_type(8)));

// ============ Fast path: 2 kernels, no global atomics, no init ============
// ws layout: [0, B_*S_) u16 idx_T  (256 KB), transposed indices idx_T[s][b].

// Kernel A: z_q gather + idx transpose. 2048 blocks x 256 threads.
// s-major mapping (s = blockIdx&31): all 64 blocks of a given s land on XCD
// s%8 (round-robin dispatch), pinning that s's 512KB emb slice in one L2.
// 64 rows/block (same s, consecutive b), 8-deep unroll -> 8 independent
// gather loads in flight per thread.
__global__ void __launch_bounds__(256)
gather_t_kernel(const int* __restrict__ idx,
                const float* __restrict__ emb,
                float* __restrict__ z_q,
                u16* __restrict__ idx_t) {
    const int s     = blockIdx.x & (S_ - 1);
    const int chunk = blockIdx.x >> 5;          // [0, 64)
    const int g     = threadIdx.x >> 5;         // row group 0..7
    const int lane  = threadIdx.x & 31;
    __shared__ int lds_k[64];
#pragma unroll
    for (int it = 0; it < 8; ++it) {
        const int b   = chunk * 64 + it * 8 + g;
        const int row = b * S_ + s;
        const int k   = idx[row];               // broadcast within 32-lane group
        if (lane == 0) lds_k[it * 8 + g] = k;
        const f4 val =
            reinterpret_cast<const f4*>(emb)[((size_t)s * K_ + k) * 32 + lane];
        __builtin_nontemporal_store(
            val, reinterpret_cast<f4*>(z_q) + (size_t)row * 32 + lane);
    }
    __syncthreads();
    if (threadIdx.x < 64)
        idx_t[(size_t)s * B_ + chunk * 64 + threadIdx.x] =
            (u16)lds_k[threadIdx.x];
}

// Kernel B: LDS histogram + n[s] + fused EMA/Laplace. 1024 blocks x 256.
// Block i: s = i&31 (XCD-aligned with kernel A's warm emb slice), k-chunk
// c = i>>5 (32 bins). Scans its s-column of idx_T (8KB, coalesced) into a
// 32-bin LDS histogram (~128 LDS atomics); n from closed form
// n = DECAY*rowsum(ecs[s]) + OMD*B  (sum_k counts == B exactly).
__global__ void __launch_bounds__(256)
ema_hist_kernel(const u16* __restrict__ idx_t,
                const float* __restrict__ emb,
                const float* __restrict__ ecs_in,
                const float* __restrict__ ema_w,
                float* __restrict__ new_ecs_out,
                float* __restrict__ new_ema_w_out,
                float* __restrict__ new_emb_out) {
    const int s     = blockIdx.x & (S_ - 1);
    const int c     = blockIdx.x >> 5;          // k-chunk [0, 32)
    const int t     = threadIdx.x;
    const int kbase = c * 32;

    __shared__ int   hist[32];
    __shared__ float red[4];
    __shared__ float n_sh;
    if (t < 32) hist[t] = 0;
    __syncthreads();

    // Histogram scan: 4096 u16 = 512 ushort8; 2 per thread, coalesced.
    const us8* col = reinterpret_cast<const us8*>(idx_t + (size_t)s * B_);
#pragma unroll
    for (int it = 0; it < 2; ++it) {
        const us8 v = col[it * 256 + t];
#pragma unroll
        for (int j = 0; j < 8; ++j) {
            const unsigned u = (unsigned)v[j] - (unsigned)kbase;
            if (u < 32u) atomicAdd(&hist[u], 1);
        }
    }

    // n[s] via closed form.
    const f4 v = reinterpret_cast<const f4*>(ecs_in + s * K_)[t];
    float local = v.x + v.y + v.z + v.w;
#pragma unroll
    for (int off = 1; off < 64; off <<= 1) local += __shfl_xor(local, off);
    if ((t & 63) == 0) red[t >> 6] = local;
    __syncthreads();                 // also publishes hist atomics
    if (t == 0)
        n_sh = DECAY * (red[0] + red[1] + red[2] + red[3]) + OMD * (float)B_;
    __syncthreads();
    const float n = n_sh;
    const float denom_inv = 1.0f / (n + (float)K_ * EPS);

    // Fused EMA elementwise: 1024 f4 per block (32 bins x 32 f4).
    const size_t base = ((size_t)s * K_ + kbase) * 32;   // f4 base
#pragma unroll
    for (int it = 0; it < 4; ++it) {
        const int    off = it * 256 + t;
        const int    ub  = off >> 5;             // local bin [0, 32)
        const size_t e   = base + off;           // global f4 index
        const int    sk  = (int)(e >> 5);
        const float ccount = (float)hist[ub];
        const float ne = DECAY * ecs_in[sk] + OMD * ccount;
        const float cs = (ne + EPS) * denom_inv * n;
        if ((off & 31) == 0) new_ecs_out[sk] = ne;

        const f4 w  = reinterpret_cast<const f4*>(ema_w)[e];
        const f4 em = reinterpret_cast<const f4*>(emb)[e];
        f4 nw;
        nw.x = DECAY * w.x + OMD * ccount * em.x;
        nw.y = DECAY * w.y + OMD * ccount * em.y;
        nw.z = DECAY * w.z + OMD * ccount * em.z;
        nw.w = DECAY * w.w + OMD * ccount * em.w;
        __builtin_nontemporal_store(nw, reinterpret_cast<f4*>(new_ema_w_out) + e);
        const float inv = 1.0f / cs;
        f4 nb;
        nb.x = nw.x * inv;
        nb.y = nw.y * inv;
        nb.z = nw.z * inv;
        nb.w = nw.w * inv;
        __builtin_nontemporal_store(nb, reinterpret_cast<f4*>(new_emb_out) + e);
    }
}

// ============ Fallback path (proven R6 structure), used if ws < 256 KB ============

__global__ void __launch_bounds__(256)
init_kernel(const float* __restrict__ ecs_in,
            int* __restrict__ counts,
            float* __restrict__ n_out) {
    const int s = blockIdx.x;
    const int t = threadIdx.x;
    reinterpret_cast<i4*>(counts + s * K_)[t] = i4{0, 0, 0, 0};
    const f4 v = reinterpret_cast<const f4*>(ecs_in + s * K_)[t];
    float local = v.x + v.y + v.z + v.w;
#pragma unroll
    for (int off = 1; off < 64; off <<= 1) local += __shfl_xor(local, off);
    __shared__ float red[4];
    if ((t & 63) == 0) red[t >> 6] = local;
    __syncthreads();
    if (t == 0)
        n_out[s] = DECAY * (red[0] + red[1] + red[2] + red[3]) + OMD * (float)B_;
}

__global__ void __launch_bounds__(256)
gather_hist_kernel(const int* __restrict__ idx,
                   const float* __restrict__ emb,
                   float* __restrict__ z_q,
                   int* __restrict__ counts) {
    const int s     = blockIdx.x & (S_ - 1);
    const int chunk = blockIdx.x >> 5;
    const int g     = threadIdx.x >> 5;
    const int lane  = threadIdx.x & 31;
    const int b     = chunk * 8 + g;
    const int row   = b * S_ + s;
    const int k     = idx[row];
    if (lane == 0) atomicAdd(&counts[s * K_ + k], 1);
    const f4 val =
        reinterpret_cast<const f4*>(emb)[((size_t)s * K_ + k) * 32 + lane];
    __builtin_nontemporal_store(
        val, reinterpret_cast<f4*>(z_q) + (size_t)row * 32 + lane);
}

__global__ void __launch_bounds__(256)
ema_kernel(const float* __restrict__ ema_w,
           const float* __restrict__ emb,
           const float* __restrict__ ecs_in,
           const int* __restrict__ counts,
           const float* __restrict__ n_arr,
           float* __restrict__ new_ecs_out,
           float* __restrict__ new_ema_w_out,
           float* __restrict__ new_emb_out) {
    const int i = blockIdx.x;
    const int s = i & (S_ - 1);
    const int c = i >> 5;
    const size_t base = ((size_t)s * K_ + c * 32) * 32;
    const float n = n_arr[s];
    const float denom_inv = 1.0f / (n + (float)K_ * EPS);
#pragma unroll
    for (int it = 0; it < 4; ++it) {
        const size_t e = base + it * 256 + threadIdx.x;
        const int sk = (int)(e >> 5);
        const float ccount = (float)counts[sk];
        const float ne = DECAY * ecs_in[sk] + OMD * ccount;
        const float cs = (ne + EPS) * denom_inv * n;
        if ((e & 31) == 0) new_ecs_out[sk] = ne;
        const f4 w  = reinterpret_cast<const f4*>(ema_w)[e];
        const f4 em = reinterpret_cast<const f4*>(emb)[e];
        f4 nw;
        nw.x = DECAY * w.x + OMD * ccount * em.x;
        nw.y = DECAY * w.y + OMD * ccount * em.y;
        nw.z = DECAY * w.z + OMD * ccount * em.z;
        nw.w = DECAY * w.w + OMD * ccount * em.w;
        __builtin_nontemporal_store(nw, reinterpret_cast<f4*>(new_ema_w_out) + e);
        const float inv = 1.0f / cs;
        f4 nb;
        nb.x = nw.x * inv;
        nb.y = nw.y * inv;
        nb.z = nw.z * inv;
        nb.w = nw.w * inv;
        __builtin_nontemporal_store(nb, reinterpret_cast<f4*>(new_emb_out) + e);
    }
}

extern "C" void kernel_launch(void* const* d_in, const int* in_sizes, int n_in,
                              void* d_out, int out_size, void* d_ws, size_t ws_size,
                              hipStream_t stream) {
    const int*   idx   = (const int*)d_in[0];
    const float* emb   = (const float*)d_in[1];
    const float* ecs   = (const float*)d_in[2];
    const float* ema_w = (const float*)d_in[3];

    float* out       = (float*)d_out;
    float* z_q       = out;                                  // [B,S,D]
    float* new_emb   = z_q + (size_t)B_ * S_ * D_;           // [S,K,D]
    float* new_ecs   = new_emb + (size_t)S_ * K_ * D_;       // [S,K]
    float* new_ema_w = new_ecs + (size_t)S_ * K_;            // [S,K,D]

    if (ws_size >= (size_t)B_ * S_ * sizeof(u16)) {
        // Fast path: 2 kernels, idx_T in ws.
        u16* idx_t = (u16*)d_ws;
        gather_t_kernel<<<2048, 256, 0, stream>>>(idx, emb, z_q, idx_t);
        ema_hist_kernel<<<1024, 256, 0, stream>>>(
            idx_t, emb, ecs, ema_w, new_ecs, new_ema_w, new_emb);
    } else {
        // Fallback: proven R6 3-kernel path (counts + n in ws, 128.2 KB).
        int*   counts = (int*)d_ws;
        float* n_arr  = (float*)d_ws + (size_t)S_ * K_;
        init_kernel<<<S_, 256, 0, stream>>>(ecs, counts, n_arr);
        gather_hist_kernel<<<(B_ * S_) / 8, 256, 0, stream>>>(idx, emb, z_q, counts);
        ema_kernel<<<1024, 256, 0, stream>>>(
            ema_w, emb, ecs, counts, n_arr, new_ecs, new_ema_w, new_emb);
    }
}

// Round 8
// 30.412 us; speedup vs baseline: 9.2368x; 1.0363x over previous
//
#include <hip/hip_runtime.h>

// Problem constants
#define B_ 4096
#define S_ 32
#define K_ 1024
#define D_ 128
constexpr float DECAY = 0.99f;
constexpr float OMD   = 0.01f;     // 1 - decay
constexpr float EPS   = 1e-5f;

typedef float          f4  __attribute__((ext_vector_type(4)));
typedef int            i4  __attribute__((ext_vector_type(4)));
typedef unsigned short u16;
typedef u16            us8 __attribute__((ext_vector_type(8)));

// ============ Fast path: 2 kernels, no global atomics, no init ============
// ws layout: [0, B_*S_) u16 idx_T  (256 KB), transposed indices idx_T[s][b].

// Kernel A: z_q gather + idx transpose. 2048 blocks x 256 threads.
// s-major mapping (s = blockIdx&31): all 64 blocks of a given s land on XCD
// s%8 (round-robin dispatch), pinning that s's 512KB emb slice in one L2.
// 64 rows/block. All 8 idx loads prefetched into registers first -> 8
// independent gather loads in flight (no serial idx->gather->idx chain).
__global__ void __launch_bounds__(256)
gather_t_kernel(const int* __restrict__ idx,
                const float* __restrict__ emb,
                float* __restrict__ z_q,
                u16* __restrict__ idx_t) {
    const int s     = blockIdx.x & (S_ - 1);
    const int chunk = blockIdx.x >> 5;          // [0, 64)
    const int g     = threadIdx.x >> 5;         // row group 0..7
    const int lane  = threadIdx.x & 31;

    int kk[8];
#pragma unroll
    for (int it = 0; it < 8; ++it) {
        const int b = chunk * 64 + it * 8 + g;
        kk[it] = idx[b * S_ + s];               // broadcast within 32-lane group
    }
#pragma unroll
    for (int it = 0; it < 8; ++it) {
        const int b = chunk * 64 + it * 8 + g;
        if (lane == 0)                           // direct u16 transpose store
            idx_t[(size_t)s * B_ + b] = (u16)kk[it];
        const f4 val =
            reinterpret_cast<const f4*>(emb)[((size_t)s * K_ + kk[it]) * 32 + lane];
        __builtin_nontemporal_store(
            val, reinterpret_cast<f4*>(z_q) + ((size_t)b * S_ + s) * 32 + lane);
    }
}

// Kernel B: LDS histogram + n[s] + fused EMA/Laplace. 2048 blocks x 256.
// Block i: s = i&31 (XCD-aligned with kernel A's warm emb slice), k-chunk
// c = i>>5 of 16 bins. Scans its s-column of idx_T (8KB, coalesced) into a
// 16-bin LDS histogram; n from closed form n = DECAY*rowsum(ecs[s]) + OMD*B
// (sum_k counts == B exactly). 2 f4/thread EMA tail.
__global__ void __launch_bounds__(256)
ema_hist_kernel(const u16* __restrict__ idx_t,
                const float* __restrict__ emb,
                const float* __restrict__ ecs_in,
                const float* __restrict__ ema_w,
                float* __restrict__ new_ecs_out,
                float* __restrict__ new_ema_w_out,
                float* __restrict__ new_emb_out) {
    const int s     = blockIdx.x & (S_ - 1);
    const int c     = blockIdx.x >> 5;          // k-chunk [0, 64)
    const int t     = threadIdx.x;
    const int kbase = c * 16;

    __shared__ int   hist[16];
    __shared__ float red[4];
    __shared__ float n_sh;
    if (t < 16) hist[t] = 0;
    __syncthreads();

    // Histogram scan: 4096 u16 = 512 ushort8; 2 per thread, coalesced.
    const us8* col = reinterpret_cast<const us8*>(idx_t + (size_t)s * B_);
#pragma unroll
    for (int it = 0; it < 2; ++it) {
        const us8 v = col[it * 256 + t];
#pragma unroll
        for (int j = 0; j < 8; ++j) {
            const unsigned u = (unsigned)v[j] - (unsigned)kbase;
            if (u < 16u) atomicAdd(&hist[u], 1);
        }
    }

    // n[s] via closed form.
    const f4 v = reinterpret_cast<const f4*>(ecs_in + s * K_)[t];
    float local = v.x + v.y + v.z + v.w;
#pragma unroll
    for (int off = 1; off < 64; off <<= 1) local += __shfl_xor(local, off);
    if ((t & 63) == 0) red[t >> 6] = local;
    __syncthreads();                 // also publishes hist atomics
    if (t == 0)
        n_sh = DECAY * (red[0] + red[1] + red[2] + red[3]) + OMD * (float)B_;
    __syncthreads();
    const float n = n_sh;
    const float denom_inv = 1.0f / (n + (float)K_ * EPS);

    // Fused EMA elementwise: 512 f4 per block (16 bins x 32 f4).
    const size_t base = ((size_t)s * K_ + kbase) * 32;   // f4 base
#pragma unroll
    for (int it = 0; it < 2; ++it) {
        const int    off = it * 256 + t;
        const int    ub  = off >> 5;             // local bin [0, 16)
        const size_t e   = base + off;           // global f4 index
        const int    sk  = (int)(e >> 5);
        const float ccount = (float)hist[ub];
        const float ne = DECAY * ecs_in[sk] + OMD * ccount;
        const float cs = (ne + EPS) * denom_inv * n;
        if ((off & 31) == 0) new_ecs_out[sk] = ne;

        const f4 w  = reinterpret_cast<const f4*>(ema_w)[e];
        const f4 em = reinterpret_cast<const f4*>(emb)[e];
        f4 nw;
        nw.x = DECAY * w.x + OMD * ccount * em.x;
        nw.y = DECAY * w.y + OMD * ccount * em.y;
        nw.z = DECAY * w.z + OMD * ccount * em.z;
        nw.w = DECAY * w.w + OMD * ccount * em.w;
        __builtin_nontemporal_store(nw, reinterpret_cast<f4*>(new_ema_w_out) + e);
        const float inv = 1.0f / cs;
        f4 nb;
        nb.x = nw.x * inv;
        nb.y = nw.y * inv;
        nb.z = nw.z * inv;
        nb.w = nw.w * inv;
        __builtin_nontemporal_store(nb, reinterpret_cast<f4*>(new_emb_out) + e);
    }
}

// ============ Fallback path (proven R6 structure), used if ws < 256 KB ============

__global__ void __launch_bounds__(256)
init_kernel(const float* __restrict__ ecs_in,
            int* __restrict__ counts,
            float* __restrict__ n_out) {
    const int s = blockIdx.x;
    const int t = threadIdx.x;
    reinterpret_cast<i4*>(counts + s * K_)[t] = i4{0, 0, 0, 0};
    const f4 v = reinterpret_cast<const f4*>(ecs_in + s * K_)[t];
    float local = v.x + v.y + v.z + v.w;
#pragma unroll
    for (int off = 1; off < 64; off <<= 1) local += __shfl_xor(local, off);
    __shared__ float red[4];
    if ((t & 63) == 0) red[t >> 6] = local;
    __syncthreads();
    if (t == 0)
        n_out[s] = DECAY * (red[0] + red[1] + red[2] + red[3]) + OMD * (float)B_;
}

__global__ void __launch_bounds__(256)
gather_hist_kernel(const int* __restrict__ idx,
                   const float* __restrict__ emb,
                   float* __restrict__ z_q,
                   int* __restrict__ counts) {
    const int s     = blockIdx.x & (S_ - 1);
    const int chunk = blockIdx.x >> 5;
    const int g     = threadIdx.x >> 5;
    const int lane  = threadIdx.x & 31;
    const int b     = chunk * 8 + g;
    const int row   = b * S_ + s;
    const int k     = idx[row];
    if (lane == 0) atomicAdd(&counts[s * K_ + k], 1);
    const f4 val =
        reinterpret_cast<const f4*>(emb)[((size_t)s * K_ + k) * 32 + lane];
    __builtin_nontemporal_store(
        val, reinterpret_cast<f4*>(z_q) + (size_t)row * 32 + lane);
}

__global__ void __launch_bounds__(256)
ema_kernel(const float* __restrict__ ema_w,
           const float* __restrict__ emb,
           const float* __restrict__ ecs_in,
           const int* __restrict__ counts,
           const float* __restrict__ n_arr,
           float* __restrict__ new_ecs_out,
           float* __restrict__ new_ema_w_out,
           float* __restrict__ new_emb_out) {
    const int i = blockIdx.x;
    const int s = i & (S_ - 1);
    const int c = i >> 5;
    const size_t base = ((size_t)s * K_ + c * 32) * 32;
    const float n = n_arr[s];
    const float denom_inv = 1.0f / (n + (float)K_ * EPS);
#pragma unroll
    for (int it = 0; it < 4; ++it) {
        const size_t e = base + it * 256 + threadIdx.x;
        const int sk = (int)(e >> 5);
        const float ccount = (float)counts[sk];
        const float ne = DECAY * ecs_in[sk] + OMD * ccount;
        const float cs = (ne + EPS) * denom_inv * n;
        if ((e & 31) == 0) new_ecs_out[sk] = ne;
        const f4 w  = reinterpret_cast<const f4*>(ema_w)[e];
        const f4 em = reinterpret_cast<const f4*>(emb)[e];
        f4 nw;
        nw.x = DECAY * w.x + OMD * ccount * em.x;
        nw.y = DECAY * w.y + OMD * ccount * em.y;
        nw.z = DECAY * w.z + OMD * ccount * em.z;
        nw.w = DECAY * w.w + OMD * ccount * em.w;
        __builtin_nontemporal_store(nw, reinterpret_cast<f4*>(new_ema_w_out) + e);
        const float inv = 1.0f / cs;
        f4 nb;
        nb.x = nw.x * inv;
        nb.y = nw.y * inv;
        nb.z = nw.z * inv;
        nb.w = nw.w * inv;
        __builtin_nontemporal_store(nb, reinterpret_cast<f4*>(new_emb_out) + e);
    }
}

extern "C" void kernel_launch(void* const* d_in, const int* in_sizes, int n_in,
                              void* d_out, int out_size, void* d_ws, size_t ws_size,
                              hipStream_t stream) {
    const int*   idx   = (const int*)d_in[0];
    const float* emb   = (const float*)d_in[1];
    const float* ecs   = (const float*)d_in[2];
    const float* ema_w = (const float*)d_in[3];

    float* out       = (float*)d_out;
    float* z_q       = out;                                  // [B,S,D]
    float* new_emb   = z_q + (size_t)B_ * S_ * D_;           // [S,K,D]
    float* new_ecs   = new_emb + (size_t)S_ * K_ * D_;       // [S,K]
    float* new_ema_w = new_ecs + (size_t)S_ * K_;            // [S,K,D]

    if (ws_size >= (size_t)B_ * S_ * sizeof(u16)) {
        // Fast path: 2 kernels, idx_T in ws.
        u16* idx_t = (u16*)d_ws;
        gather_t_kernel<<<2048, 256, 0, stream>>>(idx, emb, z_q, idx_t);
        ema_hist_kernel<<<2048, 256, 0, stream>>>(
            idx_t, emb, ecs, ema_w, new_ecs, new_ema_w, new_emb);
    } else {
        // Fallback: proven R6 3-kernel path (counts + n in ws, 128.2 KB).
        int*   counts = (int*)d_ws;
        float* n_arr  = (float*)d_ws + (size_t)S_ * K_;
        init_kernel<<<S_, 256, 0, stream>>>(ecs, counts, n_arr);
        gather_hist_kernel<<<(B_ * S_) / 8, 256, 0, stream>>>(idx, emb, z_q, counts);
        ema_kernel<<<1024, 256, 0, stream>>>(
            ema_w, emb, ecs, counts, n_arr, new_ecs, new_ema_w, new_emb);
    }
}